// Round 6
// baseline (711.646 us; speedup 1.0000x reference)
//
#include <hip/hip_runtime.h>
#include <math.h>

#define B_GRAPHS 50
#define NPG0     2000
#define EPG      12000
#define F_IN_C   256
#define NHID     128
#define N0       (B_GRAPHS * NPG0)   // 100000
#define NE       (B_GRAPHS * EPG)    // 600000
#define RSEG     16                  // readout segments per graph
#define GSLOTS   7                   // ceil(50 graphs / 8 XCDs)
#define CP2      72                  // epilogue LDS stride (halves)

typedef _Float16 f16x8 __attribute__((ext_vector_type(8)));
typedef float    f32x4 __attribute__((ext_vector_type(4)));

static inline int cdiv(int a, int b) { return (a + b - 1) / b; }

// ---------------- utility fills ----------------
__global__ void k_fill_f32(float* __restrict__ p, float v, int n) {
    int i = blockIdx.x * 256 + threadIdx.x;
    if (i < n) p[i] = v;
}
// zero cnt, optionally fill mapping with -1
__global__ void k_fill2(int* __restrict__ cnt, int* __restrict__ mapping, int n, int do_map) {
    int i = blockIdx.x * 256 + threadIdx.x;
    if (i < n) {
        cnt[i] = 0;
        if (do_map) mapping[i] = -1;
    }
}

// ---------------- edge init + degree count (cnt pre-zeroed) ----------------
__global__ void k_init_edges(const int* __restrict__ ei, int* __restrict__ esrc,
                             int* __restrict__ edst, float* __restrict__ ew,
                             int* __restrict__ cnt) {
    int e = blockIdx.x * 256 + threadIdx.x;
    if (e < NE) {
        int d = ei[NE + e];
        esrc[e] = ei[e]; edst[e] = d; ew[e] = 1.0f;
        atomicAdd(&cnt[d], 1);
    }
}

// ---------------- weight convert+transpose: WT[n][k] = (fp16)W[k][n] ----------------
__global__ void k_cvt_wt(const float* __restrict__ W, _Float16* __restrict__ WT, int F) {
    int t = blockIdx.x * 256 + threadIdx.x;
    if (t >= F * 128) return;
    int n = t / F, kk = t - n * F;
    WT[t] = (_Float16)W[(size_t)kk * 128 + n];
}

// ------------- weight-stationary MFMA GEMM, 128 rows x 64 cols per block -------------
// grid (cdiv(N,128), 2). W^T 64-col slice in LDS (XOR swizzle), barrier-free K-loop,
// double-buffered A prefetch (2 K-chunks in flight per wave).
template<int FP32IN, int F>
__global__ __launch_bounds__(256) void k_gemm_ws(const void* __restrict__ Xin,
                                                 const _Float16* __restrict__ WT,
                                                 _Float16* __restrict__ H, int N) {
    constexpr int K8 = F / 8;
    constexpr int SMEMSZ = (64 * F > 128 * CP2) ? 64 * F : 128 * CP2;
    __shared__ _Float16 smem[SMEMSZ];
    const int tid  = threadIdx.x;
    const int wave = tid >> 6, lane = tid & 63;
    const int quad = lane >> 4, l16 = lane & 15;
    const int m_blk = blockIdx.x * 128;
    const int cy = blockIdx.y;           // column half

    // stage W^T slice [64][F] with chunk-XOR swizzle
    for (int c = tid; c < 64 * K8; c += 256) {
        int n = c / K8, k8 = c - n * K8;
        f16x8 v = *(const f16x8*)&WT[((size_t)(cy * 64 + n)) * F + k8 * 8];
        *(f16x8*)&smem[n * F + ((k8 ^ (n & 7)) << 3)] = v;
    }
    __syncthreads();

    f32x4 acc[2][4];
#pragma unroll
    for (int i = 0; i < 2; ++i)
#pragma unroll
        for (int j = 0; j < 4; ++j) acc[i][j] = {0.f, 0.f, 0.f, 0.f};

    int row0 = m_blk + wave * 32 + l16;
    int row1 = row0 + 16;
    if (row0 > N - 1) row0 = N - 1;
    if (row1 > N - 1) row1 = N - 1;
    const int sx = l16 & 7;
    constexpr int NKQ = F / 32;

    if (FP32IN) {
        const float* b0 = (const float*)Xin + (size_t)row0 * F + quad * 8;
        const float* b1 = (const float*)Xin + (size_t)row1 * F + quad * 8;
        float4 p[2][4];
#pragma unroll
        for (int b = 0; b < 2; ++b) {
            p[b][0] = ((const float4*)(b0 + b * 32))[0];
            p[b][1] = ((const float4*)(b0 + b * 32))[1];
            p[b][2] = ((const float4*)(b1 + b * 32))[0];
            p[b][3] = ((const float4*)(b1 + b * 32))[1];
        }
#pragma unroll
        for (int kq = 0; kq < NKQ; ++kq) {
            const int buf = kq & 1;
            float4 f0 = p[buf][0], f1 = p[buf][1], g0 = p[buf][2], g1 = p[buf][3];
            if (kq + 2 < NKQ) {
                p[buf][0] = ((const float4*)(b0 + (kq + 2) * 32))[0];
                p[buf][1] = ((const float4*)(b0 + (kq + 2) * 32))[1];
                p[buf][2] = ((const float4*)(b1 + (kq + 2) * 32))[0];
                p[buf][3] = ((const float4*)(b1 + (kq + 2) * 32))[1];
            }
            f16x8 af0 = (f16x8){(_Float16)f0.x,(_Float16)f0.y,(_Float16)f0.z,(_Float16)f0.w,
                                (_Float16)f1.x,(_Float16)f1.y,(_Float16)f1.z,(_Float16)f1.w};
            f16x8 af1 = (f16x8){(_Float16)g0.x,(_Float16)g0.y,(_Float16)g0.z,(_Float16)g0.w,
                                (_Float16)g1.x,(_Float16)g1.y,(_Float16)g1.z,(_Float16)g1.w};
            f16x8 bf[4];
#pragma unroll
            for (int j = 0; j < 4; ++j)
                bf[j] = *(const f16x8*)&smem[(j * 16 + l16) * F + ((((kq << 2) + quad) ^ sx) << 3)];
#pragma unroll
            for (int j = 0; j < 4; ++j) {
                acc[0][j] = __builtin_amdgcn_mfma_f32_16x16x32_f16(af0, bf[j], acc[0][j], 0, 0, 0);
                acc[1][j] = __builtin_amdgcn_mfma_f32_16x16x32_f16(af1, bf[j], acc[1][j], 0, 0, 0);
            }
        }
    } else {
        const _Float16* b0 = (const _Float16*)Xin + (size_t)row0 * F + quad * 8;
        const _Float16* b1 = (const _Float16*)Xin + (size_t)row1 * F + quad * 8;
        f16x8 q[2][2];
#pragma unroll
        for (int b = 0; b < 2; ++b) {
            q[b][0] = *(const f16x8*)(b0 + b * 32);
            q[b][1] = *(const f16x8*)(b1 + b * 32);
        }
#pragma unroll
        for (int kq = 0; kq < NKQ; ++kq) {
            const int buf = kq & 1;
            f16x8 af0 = q[buf][0], af1 = q[buf][1];
            if (kq + 2 < NKQ) {
                q[buf][0] = *(const f16x8*)(b0 + (kq + 2) * 32);
                q[buf][1] = *(const f16x8*)(b1 + (kq + 2) * 32);
            }
            f16x8 bf[4];
#pragma unroll
            for (int j = 0; j < 4; ++j)
                bf[j] = *(const f16x8*)&smem[(j * 16 + l16) * F + ((((kq << 2) + quad) ^ sx) << 3)];
#pragma unroll
            for (int j = 0; j < 4; ++j) {
                acc[0][j] = __builtin_amdgcn_mfma_f32_16x16x32_f16(af0, bf[j], acc[0][j], 0, 0, 0);
                acc[1][j] = __builtin_amdgcn_mfma_f32_16x16x32_f16(af1, bf[j], acc[1][j], 0, 0, 0);
            }
        }
    }
    __syncthreads();   // done reading W; reuse LDS for epilogue

    _Float16* sC = smem;                  // [128][CP2]
    const int rw = wave * 32;
#pragma unroll
    for (int i = 0; i < 2; ++i)
#pragma unroll
        for (int j = 0; j < 4; ++j)
#pragma unroll
            for (int g = 0; g < 4; ++g)
                sC[(rw + i * 16 + quad * 4 + g) * CP2 + j * 16 + l16] = (_Float16)acc[i][j][g];
    __syncthreads();
    {
        int rr = tid >> 1;
        int gr = m_blk + rr;
        if (gr < N) {
            _Float16* Hr = H + (size_t)gr * 128 + cy * 64 + (tid & 1) * 32;
            const _Float16* Sr = sC + rr * CP2 + (tid & 1) * 32;
#pragma unroll
            for (int c = 0; c < 4; ++c)
                *(f16x8*)&Hr[c * 8] = *(const f16x8*)&Sr[c * 8];
        }
    }
}

// ---------------- CSR scan (per-graph, exclusive, base b*EPG) ----------------
__global__ __launch_bounds__(256) void k_scan(const int* __restrict__ cnt,
                                              int* __restrict__ offs,
                                              int* __restrict__ cursor, int npg) {
    __shared__ int ch[256];
    int b = blockIdx.x, tid = threadIdx.x;
    int per = (npg + 255) >> 8;
    int base = b * npg;
    int s0 = tid * per;
    int s1 = s0 + per; if (s1 > npg) s1 = npg; if (s0 > npg) s0 = npg;
    int s = 0;
    for (int i = s0; i < s1; ++i) s += cnt[base + i];
    ch[tid] = s;
    __syncthreads();
    for (int d = 1; d < 256; d <<= 1) {
        int t = ch[tid] + ((tid >= d) ? ch[tid - d] : 0);
        __syncthreads();
        ch[tid] = t;
        __syncthreads();
    }
    int run = b * EPG + ch[tid] - s;
    for (int i = s0; i < s1; ++i) {
        offs[base + i] = run; cursor[base + i] = run;
        run += cnt[base + i];
    }
}

__global__ void k_fill_csr(const int* __restrict__ esrc, const int* __restrict__ edst,
                           const float* __restrict__ ew, const int* __restrict__ cnt,
                           int* __restrict__ cursor, int* __restrict__ csr_src,
                           float* __restrict__ csr_norm) {
    int e = blockIdx.x * 256 + threadIdx.x;
    if (e < NE) {
        if (ew[e] > 0.f) {
            int sN = esrc[e], d = edst[e];
            int pos = atomicAdd(&cursor[d], 1);
            csr_src[pos] = sN;
            csr_norm[pos] = rsqrtf((float)(cnt[sN] + 1)) * rsqrtf((float)(cnt[d] + 1));
        }
    }
}

// -------- aggregation + fused score projection, 4-edge ILP + XCD swizzle --------
__global__ __launch_bounds__(256) void k_agg(const _Float16* __restrict__ H,
                                             const int* __restrict__ csr_src,
                                             const float* __restrict__ csr_norm,
                                             const int* __restrict__ offs,
                                             const int* __restrict__ cnt,
                                             const float* __restrict__ bias,
                                             const float* __restrict__ Ws,
                                             _Float16* __restrict__ X,
                                             float* __restrict__ hs,
                                             int bpg, int npg) {
    int bi = blockIdx.x;
    int x = bi & 7, s = bi >> 3;
    int gslot = s / bpg, blk = s - gslot * bpg;
    int g = x + 8 * gslot;
    if (g >= B_GRAPHS) return;
    int node = g * npg + blk * 4 + (threadIdx.x >> 6);
    int lane = threadIdx.x & 63;
    int quad = lane >> 4, l16 = lane & 15;

    int st = offs[node], c = cnt[node], en = st + c;
    float acc[8];
#pragma unroll
    for (int j = 0; j < 8; ++j) acc[j] = 0.f;

    for (int e0 = st; e0 < en; e0 += 4) {
        int e = e0 + quad;
        if (e < en) {
            int u = csr_src[e];
            float nrm = csr_norm[e];
            f16x8 h = *(const f16x8*)&H[(size_t)u * NHID + l16 * 8];
#pragma unroll
            for (int j = 0; j < 8; ++j) acc[j] = fmaf((float)h[j], nrm, acc[j]);
        }
    }
#pragma unroll
    for (int j = 0; j < 8; ++j) {
        acc[j] += __shfl_xor(acc[j], 16, 64);
        acc[j] += __shfl_xor(acc[j], 32, 64);
    }
    float invd = 1.f / (float)(c + 1);
    f16x8 hn = *(const f16x8*)&H[(size_t)node * NHID + l16 * 8];
    float4 b0 = *(const float4*)&bias[l16 * 8];
    float4 b1 = *(const float4*)&bias[l16 * 8 + 4];
    float4 w0 = *(const float4*)&Ws[l16 * 8];
    float4 w1 = *(const float4*)&Ws[l16 * 8 + 4];
    const float bb[8] = {b0.x, b0.y, b0.z, b0.w, b1.x, b1.y, b1.z, b1.w};
    const float ww[8] = {w0.x, w0.y, w0.z, w0.w, w1.x, w1.y, w1.z, w1.w};
    float sd = 0.f;
    f16x8 o;
#pragma unroll
    for (int j = 0; j < 8; ++j) {
        float v = fmaxf(acc[j] + (float)hn[j] * invd + bb[j], 0.f);
        o[j] = (_Float16)v;
        sd = fmaf(v, ww[j], sd);
    }
    if (quad == 0)
        *(f16x8*)&X[(size_t)node * NHID + l16 * 8] = o;
    sd += __shfl_xor(sd, 1, 64);
    sd += __shfl_xor(sd, 2, 64);
    sd += __shfl_xor(sd, 4, 64);
    sd += __shfl_xor(sd, 8, 64);
    if (lane == 0) hs[node] = sd;
}

// ---------------- score aggregation (scalar GCN) ----------------
__global__ void k_score(const float* __restrict__ hs, const int* __restrict__ csr_src,
                        const float* __restrict__ csr_norm, const int* __restrict__ offs,
                        const int* __restrict__ cnt, const float* __restrict__ bs,
                        float* __restrict__ score, int N) {
    int i = blockIdx.x * 256 + threadIdx.x;
    if (i >= N) return;
    int s = offs[i], c = cnt[i];
    float a = 0.f;
    for (int e = s; e < s + c; ++e) a = fmaf(hs[csr_src[e]], csr_norm[e], a);
    score[i] = a + hs[i] / (float)(c + 1) + bs[0];
}

// ---------------- top-k by O(n^2) rank counting (barrier-light, exact top_k ties) ----------------
// key = mono(score)<<32 | ~idx ; rank = #{key_j > key_i}; kept iff rank < k, new index = rank.
__global__ __launch_bounds__(256) void k_topk_rank(const float* __restrict__ score,
                                                   int* __restrict__ mapping,
                                                   int* __restrict__ perm,
                                                   float* __restrict__ gate,
                                                   int npg, int k) {
    __shared__ unsigned long long keys[2048];
    int g = blockIdx.y, tid = threadIdx.x;
    const float* sg = score + (size_t)g * npg;
    for (int i = tid; i < npg; i += 256) {
        unsigned u = __float_as_uint(sg[i]);
        u ^= (u >> 31) ? 0xFFFFFFFFu : 0x80000000u;
        keys[i] = ((unsigned long long)u << 32) | (unsigned)(0x7FFFFFFF - i);
    }
    __syncthreads();
    int i = blockIdx.x * 256 + tid;
    if (i >= npg) return;
    float si = sg[i];
    unsigned u = __float_as_uint(si);
    u ^= (u >> 31) ? 0xFFFFFFFFu : 0x80000000u;
    unsigned long long ki = ((unsigned long long)u << 32) | (unsigned)(0x7FFFFFFF - i);
    int rank = 0;
#pragma unroll 4
    for (int j = 0; j < npg; ++j)
        rank += (keys[j] > ki) ? 1 : 0;
    if (rank < k) {
        int oldg = g * npg + i, newg = g * k + rank;
        perm[newg] = oldg;
        mapping[oldg] = newg;
        gate[newg] = tanhf(si);
    }
}

// ---------------- fused pool + partial readout ----------------
__global__ __launch_bounds__(128) void k_pool_readout(const _Float16* __restrict__ X,
                                                      const float* __restrict__ gate,
                                                      const int* __restrict__ perm,
                                                      _Float16* __restrict__ XP,
                                                      float* __restrict__ pmax,
                                                      float* __restrict__ psum,
                                                      int k, int wxp) {
    int s = blockIdx.x, b = blockIdx.y, f = threadIdx.x;
    int j0 = (k * s) / RSEG, j1 = (k * (s + 1)) / RSEG;
    float mx = -__builtin_inff(), sm = 0.f;
    for (int j = j0; j < j1; ++j) {
        int g = b * k + j;
        int old = perm[g];
        float v = (float)X[(size_t)old * NHID + f] * gate[g];
        if (wxp) XP[(size_t)g * NHID + f] = (_Float16)v;
        mx = fmaxf(mx, v);
        sm += v;
    }
    pmax[(size_t)(b * RSEG + s) * NHID + f] = mx;
    psum[(size_t)(b * RSEG + s) * NHID + f] = sm;
}

__global__ __launch_bounds__(128) void k_readout_comb(const float* __restrict__ pmax,
                                                      const float* __restrict__ psum,
                                                      float* __restrict__ accum, int k) {
    int b = blockIdx.x, f = threadIdx.x;
    float mx = -__builtin_inff(), sm = 0.f;
#pragma unroll
    for (int s = 0; s < RSEG; ++s) {
        mx = fmaxf(mx, pmax[(size_t)(b * RSEG + s) * NHID + f]);
        sm += psum[(size_t)(b * RSEG + s) * NHID + f];
    }
    accum[b * 256 + f]       += mx;
    accum[b * 256 + 128 + f] += sm / (float)k;
}

// ---------------- edge remap (in place) + next-layer degree count ----------------
__global__ void k_remap(int* __restrict__ esrc, int* __restrict__ edst,
                        float* __restrict__ ew, const int* __restrict__ mapping,
                        int* __restrict__ cntN) {
    int e = blockIdx.x * 256 + threadIdx.x;
    if (e >= NE) return;
    int sN = esrc[e], d = edst[e];
    float we = ew[e];
    int ns = mapping[sN], nd = mapping[d];
    bool valid = (ns >= 0) && (nd >= 0) && (we > 0.f);
    esrc[e] = valid ? ns : 0;
    edst[e] = valid ? nd : 0;
    ew[e] = valid ? we : 0.f;
    if (valid) atomicAdd(&cntN[nd], 1);
}

// ---------------- final: out = relu(accum @ Wl + bl) ----------------
__global__ __launch_bounds__(128) void k_final(const float* __restrict__ accum,
                                               const float* __restrict__ Wl,
                                               const float* __restrict__ bl,
                                               float* __restrict__ out) {
    __shared__ float a[256];
    int b = blockIdx.x, o = threadIdx.x;
    for (int i = o; i < 256; i += 128) a[i] = accum[b * 256 + i];
    __syncthreads();
    float s = bl[o];
    for (int i = 0; i < 256; ++i) s = fmaf(a[i], Wl[i * NHID + o], s);
    out[b * NHID + o] = fmaxf(s, 0.f);
}

extern "C" void kernel_launch(void* const* d_in, const int* in_sizes, int n_in,
                              void* d_out, int out_size, void* d_ws, size_t ws_size,
                              hipStream_t stream) {
    const float* x0 = (const float*)d_in[0];
    const float* Wm[3] = {(const float*)d_in[1], (const float*)d_in[5], (const float*)d_in[9]};
    const float* bm[3] = {(const float*)d_in[2], (const float*)d_in[6], (const float*)d_in[10]};
    const float* Wsc[3] = {(const float*)d_in[3], (const float*)d_in[7], (const float*)d_in[11]};
    const float* bsc[3] = {(const float*)d_in[4], (const float*)d_in[8], (const float*)d_in[12]};
    const float* Wl = (const float*)d_in[13];
    const float* bl = (const float*)d_in[14];
    const int*   ei = (const int*)d_in[15];
    float* out = (float*)d_out;

    _Float16* bufA = (_Float16*)d_ws;                       // N0*128 halves
    _Float16* bufB = bufA + (size_t)N0 * NHID;              // N0*128
    _Float16* WT1  = bufB + (size_t)N0 * NHID;              // 128*256
    _Float16* WT2  = WT1 + 128 * 256;                       // 128*128
    _Float16* WT3  = WT2 + 128 * 128;                       // 128*128
    float* hs     = (float*)(WT3 + 128 * 128);              // N0
    float* score  = hs + N0;                                // N0
    float* gate   = score + N0;                             // N0
    float* accum  = gate + N0;                              // B*256
    float* pmax   = accum + B_GRAPHS * 256;                 // B*RSEG*128
    float* psum   = pmax + B_GRAPHS * RSEG * NHID;          // B*RSEG*128
    int*   cntA   = (int*)(psum + B_GRAPHS * RSEG * NHID);  // N0
    int*   cntB   = cntA + N0;                              // N0
    int*   offs   = cntB + N0;                              // N0
    int*   cursor = offs + N0;                              // N0
    int*   mapping= cursor + N0;                            // N0
    int*   perm   = mapping + N0;                           // N0
    int*   esrc   = perm + N0;                              // NE
    int*   edst   = esrc + NE;                              // NE
    float* ew     = (float*)(edst + NE);                    // NE
    int*   csr_src= (int*)(ew + NE);                        // NE
    float* csr_norm = (float*)(csr_src + NE);               // NE

    _Float16* WTs[3] = {WT1, WT2, WT3};
    const int EG = cdiv(NE, 256);
    const int N0G = cdiv(N0, 256);

    k_fill2<<<N0G, 256, 0, stream>>>(cntA, mapping, N0, 0);
    k_init_edges<<<EG, 256, 0, stream>>>(ei, esrc, edst, ew, cntA);
    k_fill_f32<<<cdiv(B_GRAPHS * 256, 256), 256, 0, stream>>>(accum, 0.f, B_GRAPHS * 256);
    k_cvt_wt<<<cdiv(256 * 128, 256), 256, 0, stream>>>(Wm[0], WT1, 256);
    k_cvt_wt<<<cdiv(128 * 128, 256), 256, 0, stream>>>(Wm[1], WT2, 128);
    k_cvt_wt<<<cdiv(128 * 128, 256), 256, 0, stream>>>(Wm[2], WT3, 128);

    int npg = NPG0;
    const void* xin = (const void*)x0;
    _Float16* Hbuf = bufA; _Float16* Xbuf = bufB; _Float16* XPbuf = bufA;

    for (int layer = 0; layer < 3; ++layer) {
        int N = B_GRAPHS * npg;
        int k = (npg * 4) / 5;   // ceil(0.8*n) exact for 2000/1600/1280
        int NG = cdiv(N, 256);
        int bpg = npg >> 2;      // blocks per graph in k_agg
        int* cnt  = (layer == 1) ? cntB : cntA;
        int* cntN = (layer == 0) ? cntB : cntA;

        if (layer < 2) k_fill2<<<NG, 256, 0, stream>>>(cntN, mapping, N, 1);

        if (layer == 0)
            k_gemm_ws<1, 256><<<dim3(cdiv(N, 128), 2), 256, 0, stream>>>(xin, WTs[layer], Hbuf, N);
        else
            k_gemm_ws<0, 128><<<dim3(cdiv(N, 128), 2), 256, 0, stream>>>(xin, WTs[layer], Hbuf, N);
        k_scan<<<B_GRAPHS, 256, 0, stream>>>(cnt, offs, cursor, npg);
        k_fill_csr<<<EG, 256, 0, stream>>>(esrc, edst, ew, cnt, cursor, csr_src, csr_norm);
        k_agg<<<8 * GSLOTS * bpg, 256, 0, stream>>>(Hbuf, csr_src, csr_norm, offs, cnt,
                                                    bm[layer], Wsc[layer], Xbuf, hs, bpg, npg);
        k_score<<<NG, 256, 0, stream>>>(hs, csr_src, csr_norm, offs, cnt, bsc[layer], score, N);
        k_topk_rank<<<dim3(cdiv(npg, 256), B_GRAPHS), 256, 0, stream>>>(score, mapping, perm, gate, npg, k);
        k_pool_readout<<<dim3(RSEG, B_GRAPHS), 128, 0, stream>>>(Xbuf, gate, perm, XPbuf, pmax, psum,
                                                                 k, layer < 2 ? 1 : 0);
        if (layer < 2) k_remap<<<EG, 256, 0, stream>>>(esrc, edst, ew, mapping, cntN);
        k_readout_comb<<<B_GRAPHS, 128, 0, stream>>>(pmax, psum, accum, k);

        xin = (const void*)XPbuf;
        npg = k;
        if (layer == 0) { Hbuf = bufB; Xbuf = bufA; XPbuf = bufB; }
        else            { Hbuf = bufA; Xbuf = bufB; XPbuf = bufA; }
    }

    k_final<<<B_GRAPHS, 128, 0, stream>>>(accum, Wl, bl, out);
}

// Round 7
// 650.659 us; speedup vs baseline: 1.0937x; 1.0937x over previous
//
#include <hip/hip_runtime.h>
#include <math.h>

#define B_GRAPHS 50
#define NPG0     2000
#define EPG      12000
#define F_IN_C   256
#define NHID     128
#define N0       (B_GRAPHS * NPG0)   // 100000
#define NE       (B_GRAPHS * EPG)    // 600000
#define RSEG     16                  // readout segments per graph
#define GSLOTS   7                   // ceil(50 graphs / 8 XCDs)
#define CPAD     136

typedef _Float16 f16x8 __attribute__((ext_vector_type(8)));
typedef float    f32x4 __attribute__((ext_vector_type(4)));

static inline int cdiv(int a, int b) { return (a + b - 1) / b; }

// ---------------- startup fill: zero cnt (N0) + accum ----------------
__global__ void k_fill_start(int* __restrict__ cnt, float* __restrict__ accum) {
    int i = blockIdx.x * 256 + threadIdx.x;
    if (i < N0) cnt[i] = 0;
    if (i < B_GRAPHS * 256) accum[i] = 0.f;
}

// ---------------- edge init + degree count (cnt pre-zeroed) ----------------
__global__ void k_init_edges(const int* __restrict__ ei, int* __restrict__ esrc,
                             int* __restrict__ edst, float* __restrict__ ew,
                             int* __restrict__ cnt) {
    int e = blockIdx.x * 256 + threadIdx.x;
    if (e < NE) {
        int d = ei[NE + e];
        esrc[e] = ei[e]; edst[e] = d; ew[e] = 1.0f;
        atomicAdd(&cnt[d], 1);
    }
}

// ---------------- all three weight transposes in one launch ----------------
__global__ void k_cvt_all(const float* __restrict__ W1, const float* __restrict__ W2,
                          const float* __restrict__ W3, _Float16* __restrict__ WT1,
                          _Float16* __restrict__ WT2, _Float16* __restrict__ WT3) {
    int t = blockIdx.x * 256 + threadIdx.x;   // grid exactly 65536
    if (t < 128 * 256) {
        int n = t >> 8, kk = t & 255;
        WT1[t] = (_Float16)W1[kk * 128 + n];
    } else if (t < 128 * 256 + 128 * 128) {
        int u = t - 32768; int n = u >> 7, kk = u & 127;
        WT2[u] = (_Float16)W2[kk * 128 + n];
    } else {
        int u = t - 49152; int n = u >> 7, kk = u & 127;
        WT3[u] = (_Float16)W3[kk * 128 + n];
    }
}

// ---------------- weight-stationary MFMA GEMM: H[N x 128](fp16) ----------------
// Full W^T[128][F] in LDS (XOR swizzle), barrier-free unrolled K-loop.
// GATHER: A row r comes from Xin[perm[r]] scaled by gate[r] (pool fused into GEMM).
template<int FP32IN, int F, int GATHER>
__global__ __launch_bounds__(256) void k_gemm_ws(const void* __restrict__ Xin,
                                                 const _Float16* __restrict__ WT,
                                                 const int* __restrict__ perm,
                                                 const float* __restrict__ gate,
                                                 _Float16* __restrict__ H, int N) {
    constexpr int SMEMSZ = (F * 128 > 128 * CPAD) ? F * 128 : 128 * CPAD;
    __shared__ _Float16 smem[SMEMSZ];
    const int tid  = threadIdx.x;
    const int wave = tid >> 6, lane = tid & 63;
    const int quad = lane >> 4, l16 = lane & 15;
    const int m_blk = blockIdx.x * 128;

    constexpr int K8 = F / 8;
#pragma unroll
    for (int c = tid; c < 128 * K8; c += 256) {
        int n = c / K8, k8 = c - n * K8;
        f16x8 v = *(const f16x8*)&WT[(size_t)c * 8];
        *(f16x8*)&smem[n * F + ((k8 ^ (n & 7)) << 3)] = v;
    }
    __syncthreads();

    f32x4 acc[2][8];
#pragma unroll
    for (int i = 0; i < 2; ++i)
#pragma unroll
        for (int j = 0; j < 8; ++j) acc[i][j] = {0.f, 0.f, 0.f, 0.f};

    int row0 = m_blk + wave * 32 + l16;
    int row1 = row0 + 16;
    if (row0 > N - 1) row0 = N - 1;
    if (row1 > N - 1) row1 = N - 1;
    _Float16 g0 = (_Float16)1.0f, g1 = (_Float16)1.0f;
    if (GATHER) {
        g0 = (_Float16)gate[row0]; g1 = (_Float16)gate[row1];
        row0 = perm[row0]; row1 = perm[row1];
    }
    const int sx = l16 & 7;

#pragma unroll
    for (int kq = 0; kq < F / 32; ++kq) {
        f16x8 af0, af1;
        if (FP32IN) {
            const float4* X0 = (const float4*)((const float*)Xin + (size_t)row0 * F + kq * 32 + quad * 8);
            const float4* X1 = (const float4*)((const float*)Xin + (size_t)row1 * F + kq * 32 + quad * 8);
            float4 f0 = X0[0], f1 = X0[1], g0v = X1[0], g1v = X1[1];
            af0 = (f16x8){(_Float16)f0.x,(_Float16)f0.y,(_Float16)f0.z,(_Float16)f0.w,
                          (_Float16)f1.x,(_Float16)f1.y,(_Float16)f1.z,(_Float16)f1.w};
            af1 = (f16x8){(_Float16)g0v.x,(_Float16)g0v.y,(_Float16)g0v.z,(_Float16)g0v.w,
                          (_Float16)g1v.x,(_Float16)g1v.y,(_Float16)g1v.z,(_Float16)g1v.w};
        } else {
            af0 = *(const f16x8*)((const _Float16*)Xin + (size_t)row0 * F + kq * 32 + quad * 8);
            af1 = *(const f16x8*)((const _Float16*)Xin + (size_t)row1 * F + kq * 32 + quad * 8);
            if (GATHER) { af0 = af0 * g0; af1 = af1 * g1; }
        }
        f16x8 bf[8];
#pragma unroll
        for (int j = 0; j < 8; ++j)
            bf[j] = *(const f16x8*)&smem[(j * 16 + l16) * F + ((((kq << 2) + quad) ^ sx) << 3)];
#pragma unroll
        for (int j = 0; j < 8; ++j) {
            acc[0][j] = __builtin_amdgcn_mfma_f32_16x16x32_f16(af0, bf[j], acc[0][j], 0, 0, 0);
            acc[1][j] = __builtin_amdgcn_mfma_f32_16x16x32_f16(af1, bf[j], acc[1][j], 0, 0, 0);
        }
    }
    __syncthreads();   // done reading W; reuse LDS for epilogue

    _Float16* sC = smem;                  // [128][CPAD]
    const int rw = wave * 32;
#pragma unroll
    for (int i = 0; i < 2; ++i)
#pragma unroll
        for (int j = 0; j < 8; ++j)
#pragma unroll
            for (int g = 0; g < 4; ++g)
                sC[(rw + i * 16 + quad * 4 + g) * CPAD + j * 16 + l16] = (_Float16)acc[i][j][g];
    __syncthreads();
    {
        int rr = tid >> 1;
        int gr = m_blk + rr;
        if (gr < N) {
            _Float16* Hr = H + (size_t)gr * 128 + (tid & 1) * 64;
            const _Float16* Sr = sC + rr * CPAD + (tid & 1) * 64;
#pragma unroll
            for (int c = 0; c < 8; ++c)
                *(f16x8*)&Hr[c * 8] = *(const f16x8*)&Sr[c * 8];
        }
    }
}

// ---------------- CSR scan (per-graph, exclusive, base b*EPG) ----------------
__global__ __launch_bounds__(256) void k_scan(const int* __restrict__ cnt,
                                              int* __restrict__ offs,
                                              int* __restrict__ cursor, int npg) {
    __shared__ int ch[256];
    int b = blockIdx.x, tid = threadIdx.x;
    int per = (npg + 255) >> 8;
    int base = b * npg;
    int s0 = tid * per;
    int s1 = s0 + per; if (s1 > npg) s1 = npg; if (s0 > npg) s0 = npg;
    int s = 0;
    for (int i = s0; i < s1; ++i) s += cnt[base + i];
    ch[tid] = s;
    __syncthreads();
    for (int d = 1; d < 256; d <<= 1) {
        int t = ch[tid] + ((tid >= d) ? ch[tid - d] : 0);
        __syncthreads();
        ch[tid] = t;
        __syncthreads();
    }
    int run = b * EPG + ch[tid] - s;
    for (int i = s0; i < s1; ++i) {
        offs[base + i] = run; cursor[base + i] = run;
        run += cnt[base + i];
    }
}

__global__ void k_fill_csr(const int* __restrict__ esrc, const int* __restrict__ edst,
                           const float* __restrict__ ew, const int* __restrict__ cnt,
                           int* __restrict__ cursor, int* __restrict__ csr_src,
                           float* __restrict__ csr_norm) {
    int e = blockIdx.x * 256 + threadIdx.x;
    if (e < NE) {
        if (ew[e] > 0.f) {
            int sN = esrc[e], d = edst[e];
            int pos = atomicAdd(&cursor[d], 1);
            csr_src[pos] = sN;
            csr_norm[pos] = rsqrtf((float)(cnt[sN] + 1)) * rsqrtf((float)(cnt[d] + 1));
        }
    }
}

// -------- aggregation + fused score projection, 8-edge pipeline + XCD swizzle --------
__global__ __launch_bounds__(256) void k_agg(const _Float16* __restrict__ H,
                                             const int* __restrict__ csr_src,
                                             const float* __restrict__ csr_norm,
                                             const int* __restrict__ offs,
                                             const int* __restrict__ cnt,
                                             const float* __restrict__ bias,
                                             const float* __restrict__ Ws,
                                             _Float16* __restrict__ X,
                                             float* __restrict__ hs,
                                             int bpg, int npg) {
    int bi = blockIdx.x;
    int x = bi & 7, s = bi >> 3;
    int gslot = s / bpg, blk = s - gslot * bpg;
    int g = x + 8 * gslot;
    if (g >= B_GRAPHS) return;
    int node = g * npg + blk * 4 + (threadIdx.x >> 6);
    int lane = threadIdx.x & 63;
    int quad = lane >> 4, l16 = lane & 15;

    int st = offs[node], c = cnt[node], en = st + c;
    float acc[8];
#pragma unroll
    for (int j = 0; j < 8; ++j) acc[j] = 0.f;

    if (c > 0) {
        for (int e0 = st; e0 < en; e0 += 8) {
            int eA = e0 + quad, eB = eA + 4;
            int ecA = eA < en ? eA : en - 1;
            int ecB = eB < en ? eB : en - 1;
            int uA = csr_src[ecA], uB = csr_src[ecB];
            float nA = (eA < en) ? csr_norm[ecA] : 0.f;
            float nB = (eB < en) ? csr_norm[ecB] : 0.f;
            f16x8 hA = *(const f16x8*)&H[(size_t)uA * NHID + l16 * 8];
            f16x8 hB = *(const f16x8*)&H[(size_t)uB * NHID + l16 * 8];
#pragma unroll
            for (int j = 0; j < 8; ++j) acc[j] = fmaf((float)hA[j], nA, acc[j]);
#pragma unroll
            for (int j = 0; j < 8; ++j) acc[j] = fmaf((float)hB[j], nB, acc[j]);
        }
    }
#pragma unroll
    for (int j = 0; j < 8; ++j) {
        acc[j] += __shfl_xor(acc[j], 16, 64);
        acc[j] += __shfl_xor(acc[j], 32, 64);
    }
    float invd = 1.f / (float)(c + 1);
    f16x8 hn = *(const f16x8*)&H[(size_t)node * NHID + l16 * 8];
    float4 b0 = *(const float4*)&bias[l16 * 8];
    float4 b1 = *(const float4*)&bias[l16 * 8 + 4];
    float4 w0 = *(const float4*)&Ws[l16 * 8];
    float4 w1 = *(const float4*)&Ws[l16 * 8 + 4];
    const float bb[8] = {b0.x, b0.y, b0.z, b0.w, b1.x, b1.y, b1.z, b1.w};
    const float ww[8] = {w0.x, w0.y, w0.z, w0.w, w1.x, w1.y, w1.z, w1.w};
    float sd = 0.f;
    f16x8 o;
#pragma unroll
    for (int j = 0; j < 8; ++j) {
        float v = fmaxf(acc[j] + (float)hn[j] * invd + bb[j], 0.f);
        o[j] = (_Float16)v;
        sd = fmaf(v, ww[j], sd);
    }
    if (quad == 0)
        *(f16x8*)&X[(size_t)node * NHID + l16 * 8] = o;
    sd += __shfl_xor(sd, 1, 64);
    sd += __shfl_xor(sd, 2, 64);
    sd += __shfl_xor(sd, 4, 64);
    sd += __shfl_xor(sd, 8, 64);
    if (lane == 0) hs[node] = sd;
}

// ---------------- score aggregation (scalar GCN) ----------------
__global__ void k_score(const float* __restrict__ hs, const int* __restrict__ csr_src,
                        const float* __restrict__ csr_norm, const int* __restrict__ offs,
                        const int* __restrict__ cnt, const float* __restrict__ bs,
                        float* __restrict__ score, int N) {
    int i = blockIdx.x * 256 + threadIdx.x;
    if (i >= N) return;
    int s = offs[i], c = cnt[i];
    float a = 0.f;
    for (int e = s; e < s + c; ++e) a = fmaf(hs[csr_src[e]], csr_norm[e], a);
    score[i] = a + hs[i] / (float)(c + 1) + bs[0];
}

// ---------------- per-graph top-k via bitonic sort (desc score, asc idx) ----------------
// Epilogue also fills mapping for ALL nodes (kept->new, dropped->-1) and zeroes
// the next layer's cnt buffer for this graph.
__global__ __launch_bounds__(1024) void k_topk(const float* __restrict__ score,
                                               int* __restrict__ mapping,
                                               int* __restrict__ perm,
                                               float* __restrict__ gate,
                                               int* __restrict__ cntN,
                                               int npg, int k) {
    __shared__ float ss[2048];
    __shared__ int   si[2048];
    int b = blockIdx.x, tid = threadIdx.x;
    for (int i = tid; i < 2048; i += 1024) {
        if (i < npg) { ss[i] = score[b * npg + i]; si[i] = i; }
        else         { ss[i] = -__builtin_inff();  si[i] = i; }
    }
    __syncthreads();
    for (int size = 2; size <= 2048; size <<= 1) {
        for (int stride = size >> 1; stride > 0; stride >>= 1) {
            int t = tid;
            int i = ((t & ~(stride - 1)) << 1) | (t & (stride - 1));
            int j = i | stride;
            float sa = ss[i], sb = ss[j];
            int   ia = si[i], ib = si[j];
            bool b_before_a = (sb > sa) || (sb == sa && ib < ia);
            bool forward = ((i & size) == 0);
            bool doswap = forward ? b_before_a : !b_before_a;
            if (doswap) { ss[i] = sb; ss[j] = sa; si[i] = ib; si[j] = ia; }
            __syncthreads();
        }
    }
    for (int j = tid; j < npg; j += 1024) {
        int oldg = b * npg + si[j];
        if (j < k) {
            int newg = b * k + j;
            perm[newg] = oldg;
            mapping[oldg] = newg;
            gate[newg] = tanhf(ss[j]);
        } else {
            mapping[oldg] = -1;
        }
    }
    for (int j = tid; j < k; j += 1024) cntN[b * k + j] = 0;
}

// ---------------- partial readout over pooled rows (no XP materialization) ----------------
__global__ __launch_bounds__(128) void k_pool_readout(const _Float16* __restrict__ X,
                                                      const float* __restrict__ gate,
                                                      const int* __restrict__ perm,
                                                      float* __restrict__ pmax,
                                                      float* __restrict__ psum, int k) {
    int s = blockIdx.x, b = blockIdx.y, f = threadIdx.x;
    int j0 = (k * s) / RSEG, j1 = (k * (s + 1)) / RSEG;
    float mx = -__builtin_inff(), sm = 0.f;
    for (int j = j0; j < j1; ++j) {
        int g = b * k + j;
        int old = perm[g];
        float v = (float)X[(size_t)old * NHID + f] * gate[g];
        mx = fmaxf(mx, v);
        sm += v;
    }
    pmax[(size_t)(b * RSEG + s) * NHID + f] = mx;
    psum[(size_t)(b * RSEG + s) * NHID + f] = sm;
}

__global__ __launch_bounds__(128) void k_readout_comb(const float* __restrict__ pmax,
                                                      const float* __restrict__ psum,
                                                      float* __restrict__ accum, int k) {
    int b = blockIdx.x, f = threadIdx.x;
    float mx = -__builtin_inff(), sm = 0.f;
#pragma unroll
    for (int s = 0; s < RSEG; ++s) {
        mx = fmaxf(mx, pmax[(size_t)(b * RSEG + s) * NHID + f]);
        sm += psum[(size_t)(b * RSEG + s) * NHID + f];
    }
    accum[b * 256 + f]       += mx;
    accum[b * 256 + 128 + f] += sm / (float)k;
}

// ---------------- edge remap (in place) + next-layer degree count ----------------
__global__ void k_remap(int* __restrict__ esrc, int* __restrict__ edst,
                        float* __restrict__ ew, const int* __restrict__ mapping,
                        int* __restrict__ cntN) {
    int e = blockIdx.x * 256 + threadIdx.x;
    if (e >= NE) return;
    int sN = esrc[e], d = edst[e];
    float we = ew[e];
    int ns = mapping[sN], nd = mapping[d];
    bool valid = (ns >= 0) && (nd >= 0) && (we > 0.f);
    esrc[e] = valid ? ns : 0;
    edst[e] = valid ? nd : 0;
    ew[e] = valid ? we : 0.f;
    if (valid) atomicAdd(&cntN[nd], 1);
}

// ---------------- final: out = relu(accum @ Wl + bl) ----------------
__global__ __launch_bounds__(128) void k_final(const float* __restrict__ accum,
                                               const float* __restrict__ Wl,
                                               const float* __restrict__ bl,
                                               float* __restrict__ out) {
    __shared__ float a[256];
    int b = blockIdx.x, o = threadIdx.x;
    for (int i = o; i < 256; i += 128) a[i] = accum[b * 256 + i];
    __syncthreads();
    float s = bl[o];
    for (int i = 0; i < 256; ++i) s = fmaf(a[i], Wl[i * NHID + o], s);
    out[b * NHID + o] = fmaxf(s, 0.f);
}

extern "C" void kernel_launch(void* const* d_in, const int* in_sizes, int n_in,
                              void* d_out, int out_size, void* d_ws, size_t ws_size,
                              hipStream_t stream) {
    const float* x0 = (const float*)d_in[0];
    const float* Wm[3] = {(const float*)d_in[1], (const float*)d_in[5], (const float*)d_in[9]};
    const float* bm[3] = {(const float*)d_in[2], (const float*)d_in[6], (const float*)d_in[10]};
    const float* Wsc[3] = {(const float*)d_in[3], (const float*)d_in[7], (const float*)d_in[11]};
    const float* bsc[3] = {(const float*)d_in[4], (const float*)d_in[8], (const float*)d_in[12]};
    const float* Wl = (const float*)d_in[13];
    const float* bl = (const float*)d_in[14];
    const int*   ei = (const int*)d_in[15];
    float* out = (float*)d_out;

    _Float16* bufA = (_Float16*)d_ws;                       // N0*128 halves (H)
    _Float16* bufB = bufA + (size_t)N0 * NHID;              // N0*128 (X)
    _Float16* WT1  = bufB + (size_t)N0 * NHID;              // 128*256
    _Float16* WT2  = WT1 + 128 * 256;                       // 128*128
    _Float16* WT3  = WT2 + 128 * 128;                       // 128*128
    float* hs     = (float*)(WT3 + 128 * 128);              // N0
    float* score  = hs + N0;                                // N0
    float* gate   = score + N0;                             // N0
    float* accum  = gate + N0;                              // B*256
    float* pmax   = accum + B_GRAPHS * 256;                 // B*RSEG*128
    float* psum   = pmax + B_GRAPHS * RSEG * NHID;          // B*RSEG*128
    int*   cntA   = (int*)(psum + B_GRAPHS * RSEG * NHID);  // N0
    int*   cntB   = cntA + N0;                              // N0
    int*   offs   = cntB + N0;                              // N0
    int*   cursor = offs + N0;                              // N0
    int*   mapping= cursor + N0;                            // N0
    int*   perm   = mapping + N0;                           // N0
    int*   esrc   = perm + N0;                              // NE
    int*   edst   = esrc + NE;                              // NE
    float* ew     = (float*)(edst + NE);                    // NE
    int*   csr_src= (int*)(ew + NE);                        // NE
    float* csr_norm = (float*)(csr_src + NE);               // NE

    _Float16* WTs[3] = {WT1, WT2, WT3};
    const int EG = cdiv(NE, 256);

    k_fill_start<<<cdiv(N0, 256), 256, 0, stream>>>(cntA, accum);
    k_init_edges<<<EG, 256, 0, stream>>>(ei, esrc, edst, ew, cntA);
    k_cvt_all<<<256, 256, 0, stream>>>(Wm[0], Wm[1], Wm[2], WT1, WT2, WT3);

    int npg = NPG0;
    _Float16* Hbuf = bufA; _Float16* Xbuf = bufB;

    for (int layer = 0; layer < 3; ++layer) {
        int N = B_GRAPHS * npg;
        int k = (npg * 4) / 5;   // ceil(0.8*n) exact for 2000/1600/1280
        int NG = cdiv(N, 256);
        int bpg = npg >> 2;      // blocks per graph in k_agg
        int* cnt  = (layer == 1) ? cntB : cntA;
        int* cntN = (layer == 1) ? cntA : cntB;

        if (layer == 0)
            k_gemm_ws<1, 256, 0><<<cdiv(N, 128), 256, 0, stream>>>(x0, WTs[0], perm, gate, Hbuf, N);
        else
            k_gemm_ws<0, 128, 1><<<cdiv(N, 128), 256, 0, stream>>>(Xbuf, WTs[layer], perm, gate, Hbuf, N);
        k_scan<<<B_GRAPHS, 256, 0, stream>>>(cnt, offs, cursor, npg);
        k_fill_csr<<<EG, 256, 0, stream>>>(esrc, edst, ew, cnt, cursor, csr_src, csr_norm);
        k_agg<<<8 * GSLOTS * bpg, 256, 0, stream>>>(Hbuf, csr_src, csr_norm, offs, cnt,
                                                    bm[layer], Wsc[layer], Xbuf, hs, bpg, npg);
        k_score<<<NG, 256, 0, stream>>>(hs, csr_src, csr_norm, offs, cnt, bsc[layer], score, N);
        k_topk<<<B_GRAPHS, 1024, 0, stream>>>(score, mapping, perm, gate, cntN, npg, k);
        k_pool_readout<<<dim3(RSEG, B_GRAPHS), 128, 0, stream>>>(Xbuf, gate, perm, pmax, psum, k);
        if (layer < 2) k_remap<<<EG, 256, 0, stream>>>(esrc, edst, ew, mapping, cntN);
        k_readout_comb<<<B_GRAPHS, 128, 0, stream>>>(pmax, psum, accum, k);

        npg = k;
    }

    k_final<<<B_GRAPHS, 128, 0, stream>>>(accum, Wl, bl, out);
}

// Round 8
// 642.139 us; speedup vs baseline: 1.1082x; 1.0133x over previous
//
#include <hip/hip_runtime.h>
#include <math.h>

#define B_GRAPHS 50
#define NPG0     2000
#define EPG      12000
#define F_IN_C   256
#define NHID     128
#define N0       (B_GRAPHS * NPG0)   // 100000
#define NE       (B_GRAPHS * EPG)    // 600000
#define RSEG     16                  // readout segments per graph
#define GSLOTS   7                   // ceil(50 graphs / 8 XCDs)
#define CPAD     136

typedef _Float16 f16x8 __attribute__((ext_vector_type(8)));
typedef float    f32x4 __attribute__((ext_vector_type(4)));

static inline int cdiv(int a, int b) { return (a + b - 1) / b; }

// ---------------- startup fill: zero cnt (N0) + accum ----------------
__global__ void k_fill_start(int* __restrict__ cnt, float* __restrict__ accum) {
    int i = blockIdx.x * 256 + threadIdx.x;
    if (i < N0) cnt[i] = 0;
    if (i < B_GRAPHS * 256) accum[i] = 0.f;
}

// ---------------- edge init + degree count (cnt pre-zeroed) ----------------
__global__ void k_init_edges(const int* __restrict__ ei, int* __restrict__ esrc,
                             int* __restrict__ edst, float* __restrict__ ew,
                             int* __restrict__ cnt) {
    int e = blockIdx.x * 256 + threadIdx.x;
    if (e < NE) {
        int d = ei[NE + e];
        esrc[e] = ei[e]; edst[e] = d; ew[e] = 1.0f;
        atomicAdd(&cnt[d], 1);
    }
}

// ---------------- all three weight transposes in one launch ----------------
__global__ void k_cvt_all(const float* __restrict__ W1, const float* __restrict__ W2,
                          const float* __restrict__ W3, _Float16* __restrict__ WT1,
                          _Float16* __restrict__ WT2, _Float16* __restrict__ WT3) {
    int t = blockIdx.x * 256 + threadIdx.x;   // grid exactly 65536
    if (t < 128 * 256) {
        int n = t >> 8, kk = t & 255;
        WT1[t] = (_Float16)W1[kk * 128 + n];
    } else if (t < 128 * 256 + 128 * 128) {
        int u = t - 32768; int n = u >> 7, kk = u & 127;
        WT2[u] = (_Float16)W2[kk * 128 + n];
    } else {
        int u = t - 49152; int n = u >> 7, kk = u & 127;
        WT3[u] = (_Float16)W3[kk * 128 + n];
    }
}

// ---------------- weight-stationary MFMA GEMM with deep register prefetch ----------------
// Full W^T[128][F] in LDS (XOR swizzle), barrier-free unrolled K-loop.
// A-operand pipelined depth-4 (fp32) / fully prefetched (fp16) to maximize loads in flight.
// GATHER: A row r comes from Xin[perm[r]] scaled by gate[r] (pool fused into GEMM).
template<int FP32IN, int F, int GATHER>
__global__ __launch_bounds__(256) void k_gemm_ws(const void* __restrict__ Xin,
                                                 const _Float16* __restrict__ WT,
                                                 const int* __restrict__ perm,
                                                 const float* __restrict__ gate,
                                                 _Float16* __restrict__ H, int N) {
    constexpr int SMEMSZ = (F * 128 > 128 * CPAD) ? F * 128 : 128 * CPAD;
    __shared__ _Float16 smem[SMEMSZ];
    const int tid  = threadIdx.x;
    const int wave = tid >> 6, lane = tid & 63;
    const int quad = lane >> 4, l16 = lane & 15;
    const int m_blk = blockIdx.x * 128;

    constexpr int K8 = F / 8;
#pragma unroll
    for (int c = tid; c < 128 * K8; c += 256) {
        int n = c / K8, k8 = c - n * K8;
        f16x8 v = *(const f16x8*)&WT[(size_t)c * 8];
        *(f16x8*)&smem[n * F + ((k8 ^ (n & 7)) << 3)] = v;
    }
    __syncthreads();

    f32x4 acc[2][8];
#pragma unroll
    for (int i = 0; i < 2; ++i)
#pragma unroll
        for (int j = 0; j < 8; ++j) acc[i][j] = {0.f, 0.f, 0.f, 0.f};

    int row0 = m_blk + wave * 32 + l16;
    int row1 = row0 + 16;
    if (row0 > N - 1) row0 = N - 1;
    if (row1 > N - 1) row1 = N - 1;
    _Float16 g0 = (_Float16)1.0f, g1 = (_Float16)1.0f;
    if (GATHER) {
        g0 = (_Float16)gate[row0]; g1 = (_Float16)gate[row1];
        row0 = perm[row0]; row1 = perm[row1];
    }
    const int sx = l16 & 7;
    constexpr int NKQ = F / 32;

    if (FP32IN) {
        constexpr int PD = (NKQ < 4) ? NKQ : 4;
        const float* base0 = (const float*)Xin + (size_t)row0 * F + quad * 8;
        const float* base1 = (const float*)Xin + (size_t)row1 * F + quad * 8;
        float4 p0[PD][2], p1[PD][2];
#pragma unroll
        for (int i = 0; i < PD; ++i) {
            p0[i][0] = ((const float4*)(base0 + i * 32))[0];
            p0[i][1] = ((const float4*)(base0 + i * 32))[1];
            p1[i][0] = ((const float4*)(base1 + i * 32))[0];
            p1[i][1] = ((const float4*)(base1 + i * 32))[1];
        }
#pragma unroll
        for (int kq = 0; kq < NKQ; ++kq) {
            const int b = kq % PD;
            float4 f0 = p0[b][0], f1 = p0[b][1], h0 = p1[b][0], h1 = p1[b][1];
            if (kq + PD < NKQ) {
                p0[b][0] = ((const float4*)(base0 + (kq + PD) * 32))[0];
                p0[b][1] = ((const float4*)(base0 + (kq + PD) * 32))[1];
                p1[b][0] = ((const float4*)(base1 + (kq + PD) * 32))[0];
                p1[b][1] = ((const float4*)(base1 + (kq + PD) * 32))[1];
            }
            f16x8 af0 = (f16x8){(_Float16)f0.x,(_Float16)f0.y,(_Float16)f0.z,(_Float16)f0.w,
                                (_Float16)f1.x,(_Float16)f1.y,(_Float16)f1.z,(_Float16)f1.w};
            f16x8 af1 = (f16x8){(_Float16)h0.x,(_Float16)h0.y,(_Float16)h0.z,(_Float16)h0.w,
                                (_Float16)h1.x,(_Float16)h1.y,(_Float16)h1.z,(_Float16)h1.w};
            f16x8 bf[8];
#pragma unroll
            for (int j = 0; j < 8; ++j)
                bf[j] = *(const f16x8*)&smem[(j * 16 + l16) * F + ((((kq << 2) + quad) ^ sx) << 3)];
#pragma unroll
            for (int j = 0; j < 8; ++j) {
                acc[0][j] = __builtin_amdgcn_mfma_f32_16x16x32_f16(af0, bf[j], acc[0][j], 0, 0, 0);
                acc[1][j] = __builtin_amdgcn_mfma_f32_16x16x32_f16(af1, bf[j], acc[1][j], 0, 0, 0);
            }
        }
    } else {
        // F=128: full prefetch — all 2*NKQ loads issued before any MFMA
        const _Float16* base0 = (const _Float16*)Xin + (size_t)row0 * F + quad * 8;
        const _Float16* base1 = (const _Float16*)Xin + (size_t)row1 * F + quad * 8;
        f16x8 q0[NKQ], q1[NKQ];
#pragma unroll
        for (int i = 0; i < NKQ; ++i) {
            q0[i] = *(const f16x8*)(base0 + i * 32);
            q1[i] = *(const f16x8*)(base1 + i * 32);
        }
#pragma unroll
        for (int kq = 0; kq < NKQ; ++kq) {
            f16x8 af0 = q0[kq], af1 = q1[kq];
            if (GATHER) { af0 = af0 * g0; af1 = af1 * g1; }
            f16x8 bf[8];
#pragma unroll
            for (int j = 0; j < 8; ++j)
                bf[j] = *(const f16x8*)&smem[(j * 16 + l16) * F + ((((kq << 2) + quad) ^ sx) << 3)];
#pragma unroll
            for (int j = 0; j < 8; ++j) {
                acc[0][j] = __builtin_amdgcn_mfma_f32_16x16x32_f16(af0, bf[j], acc[0][j], 0, 0, 0);
                acc[1][j] = __builtin_amdgcn_mfma_f32_16x16x32_f16(af1, bf[j], acc[1][j], 0, 0, 0);
            }
        }
    }
    __syncthreads();   // done reading W; reuse LDS for epilogue

    _Float16* sC = smem;                  // [128][CPAD]
    const int rw = wave * 32;
#pragma unroll
    for (int i = 0; i < 2; ++i)
#pragma unroll
        for (int j = 0; j < 8; ++j)
#pragma unroll
            for (int g = 0; g < 4; ++g)
                sC[(rw + i * 16 + quad * 4 + g) * CPAD + j * 16 + l16] = (_Float16)acc[i][j][g];
    __syncthreads();
    {
        int rr = tid >> 1;
        int gr = m_blk + rr;
        if (gr < N) {
            _Float16* Hr = H + (size_t)gr * 128 + (tid & 1) * 64;
            const _Float16* Sr = sC + rr * CPAD + (tid & 1) * 64;
#pragma unroll
            for (int c = 0; c < 8; ++c)
                *(f16x8*)&Hr[c * 8] = *(const f16x8*)&Sr[c * 8];
        }
    }
}

// ---------------- CSR scan (per-graph, exclusive, base b*EPG) ----------------
__global__ __launch_bounds__(256) void k_scan(const int* __restrict__ cnt,
                                              int* __restrict__ offs,
                                              int* __restrict__ cursor, int npg) {
    __shared__ int ch[256];
    int b = blockIdx.x, tid = threadIdx.x;
    int per = (npg + 255) >> 8;
    int base = b * npg;
    int s0 = tid * per;
    int s1 = s0 + per; if (s1 > npg) s1 = npg; if (s0 > npg) s0 = npg;
    int s = 0;
    for (int i = s0; i < s1; ++i) s += cnt[base + i];
    ch[tid] = s;
    __syncthreads();
    for (int d = 1; d < 256; d <<= 1) {
        int t = ch[tid] + ((tid >= d) ? ch[tid - d] : 0);
        __syncthreads();
        ch[tid] = t;
        __syncthreads();
    }
    int run = b * EPG + ch[tid] - s;
    for (int i = s0; i < s1; ++i) {
        offs[base + i] = run; cursor[base + i] = run;
        run += cnt[base + i];
    }
}

__global__ void k_fill_csr(const int* __restrict__ esrc, const int* __restrict__ edst,
                           const float* __restrict__ ew, const int* __restrict__ cnt,
                           int* __restrict__ cursor, int* __restrict__ csr_src,
                           float* __restrict__ csr_norm) {
    int e = blockIdx.x * 256 + threadIdx.x;
    if (e < NE) {
        if (ew[e] > 0.f) {
            int sN = esrc[e], d = edst[e];
            int pos = atomicAdd(&cursor[d], 1);
            csr_src[pos] = sN;
            csr_norm[pos] = rsqrtf((float)(cnt[sN] + 1)) * rsqrtf((float)(cnt[d] + 1));
        }
    }
}

// -------- aggregation + fused score projection, 8-edge pipeline + XCD swizzle --------
__global__ __launch_bounds__(256) void k_agg(const _Float16* __restrict__ H,
                                             const int* __restrict__ csr_src,
                                             const float* __restrict__ csr_norm,
                                             const int* __restrict__ offs,
                                             const int* __restrict__ cnt,
                                             const float* __restrict__ bias,
                                             const float* __restrict__ Ws,
                                             _Float16* __restrict__ X,
                                             float* __restrict__ hs,
                                             int bpg, int npg) {
    int bi = blockIdx.x;
    int x = bi & 7, s = bi >> 3;
    int gslot = s / bpg, blk = s - gslot * bpg;
    int g = x + 8 * gslot;
    if (g >= B_GRAPHS) return;
    int node = g * npg + blk * 4 + (threadIdx.x >> 6);
    int lane = threadIdx.x & 63;
    int quad = lane >> 4, l16 = lane & 15;

    int st = offs[node], c = cnt[node], en = st + c;
    float acc[8];
#pragma unroll
    for (int j = 0; j < 8; ++j) acc[j] = 0.f;

    if (c > 0) {
        for (int e0 = st; e0 < en; e0 += 8) {
            int eA = e0 + quad, eB = eA + 4;
            int ecA = eA < en ? eA : en - 1;
            int ecB = eB < en ? eB : en - 1;
            int uA = csr_src[ecA], uB = csr_src[ecB];
            float nA = (eA < en) ? csr_norm[ecA] : 0.f;
            float nB = (eB < en) ? csr_norm[ecB] : 0.f;
            f16x8 hA = *(const f16x8*)&H[(size_t)uA * NHID + l16 * 8];
            f16x8 hB = *(const f16x8*)&H[(size_t)uB * NHID + l16 * 8];
#pragma unroll
            for (int j = 0; j < 8; ++j) acc[j] = fmaf((float)hA[j], nA, acc[j]);
#pragma unroll
            for (int j = 0; j < 8; ++j) acc[j] = fmaf((float)hB[j], nB, acc[j]);
        }
    }
#pragma unroll
    for (int j = 0; j < 8; ++j) {
        acc[j] += __shfl_xor(acc[j], 16, 64);
        acc[j] += __shfl_xor(acc[j], 32, 64);
    }
    float invd = 1.f / (float)(c + 1);
    f16x8 hn = *(const f16x8*)&H[(size_t)node * NHID + l16 * 8];
    float4 b0 = *(const float4*)&bias[l16 * 8];
    float4 b1 = *(const float4*)&bias[l16 * 8 + 4];
    float4 w0 = *(const float4*)&Ws[l16 * 8];
    float4 w1 = *(const float4*)&Ws[l16 * 8 + 4];
    const float bb[8] = {b0.x, b0.y, b0.z, b0.w, b1.x, b1.y, b1.z, b1.w};
    const float ww[8] = {w0.x, w0.y, w0.z, w0.w, w1.x, w1.y, w1.z, w1.w};
    float sd = 0.f;
    f16x8 o;
#pragma unroll
    for (int j = 0; j < 8; ++j) {
        float v = fmaxf(acc[j] + (float)hn[j] * invd + bb[j], 0.f);
        o[j] = (_Float16)v;
        sd = fmaf(v, ww[j], sd);
    }
    if (quad == 0)
        *(f16x8*)&X[(size_t)node * NHID + l16 * 8] = o;
    sd += __shfl_xor(sd, 1, 64);
    sd += __shfl_xor(sd, 2, 64);
    sd += __shfl_xor(sd, 4, 64);
    sd += __shfl_xor(sd, 8, 64);
    if (lane == 0) hs[node] = sd;
}

// ---------------- score aggregation (scalar GCN) ----------------
__global__ void k_score(const float* __restrict__ hs, const int* __restrict__ csr_src,
                        const float* __restrict__ csr_norm, const int* __restrict__ offs,
                        const int* __restrict__ cnt, const float* __restrict__ bs,
                        float* __restrict__ score, int N) {
    int i = blockIdx.x * 256 + threadIdx.x;
    if (i >= N) return;
    int s = offs[i], c = cnt[i];
    float a = 0.f;
    for (int e = s; e < s + c; ++e) a = fmaf(hs[csr_src[e]], csr_norm[e], a);
    score[i] = a + hs[i] / (float)(c + 1) + bs[0];
}

// ---------------- per-graph top-k via bitonic sort (desc score, asc idx) ----------------
__global__ __launch_bounds__(1024) void k_topk(const float* __restrict__ score,
                                               int* __restrict__ mapping,
                                               int* __restrict__ perm,
                                               float* __restrict__ gate,
                                               int* __restrict__ cntN,
                                               int npg, int k) {
    __shared__ float ss[2048];
    __shared__ int   si[2048];
    int b = blockIdx.x, tid = threadIdx.x;
    for (int i = tid; i < 2048; i += 1024) {
        if (i < npg) { ss[i] = score[b * npg + i]; si[i] = i; }
        else         { ss[i] = -__builtin_inff();  si[i] = i; }
    }
    __syncthreads();
    for (int size = 2; size <= 2048; size <<= 1) {
        for (int stride = size >> 1; stride > 0; stride >>= 1) {
            int t = tid;
            int i = ((t & ~(stride - 1)) << 1) | (t & (stride - 1));
            int j = i | stride;
            float sa = ss[i], sb = ss[j];
            int   ia = si[i], ib = si[j];
            bool b_before_a = (sb > sa) || (sb == sa && ib < ia);
            bool forward = ((i & size) == 0);
            bool doswap = forward ? b_before_a : !b_before_a;
            if (doswap) { ss[i] = sb; ss[j] = sa; si[i] = ib; si[j] = ia; }
            __syncthreads();
        }
    }
    for (int j = tid; j < npg; j += 1024) {
        int oldg = b * npg + si[j];
        if (j < k) {
            int newg = b * k + j;
            perm[newg] = oldg;
            mapping[oldg] = newg;
            gate[newg] = tanhf(ss[j]);
        } else {
            mapping[oldg] = -1;
        }
    }
    for (int j = tid; j < k; j += 1024) cntN[b * k + j] = 0;
}

// ---------------- partial readout over pooled rows (no XP materialization) ----------------
__global__ __launch_bounds__(128) void k_pool_readout(const _Float16* __restrict__ X,
                                                      const float* __restrict__ gate,
                                                      const int* __restrict__ perm,
                                                      float* __restrict__ pmax,
                                                      float* __restrict__ psum, int k) {
    int s = blockIdx.x, b = blockIdx.y, f = threadIdx.x;
    int j0 = (k * s) / RSEG, j1 = (k * (s + 1)) / RSEG;
    float mx = -__builtin_inff(), sm = 0.f;
    for (int j = j0; j < j1; ++j) {
        int g = b * k + j;
        int old = perm[g];
        float v = (float)X[(size_t)old * NHID + f] * gate[g];
        mx = fmaxf(mx, v);
        sm += v;
    }
    pmax[(size_t)(b * RSEG + s) * NHID + f] = mx;
    psum[(size_t)(b * RSEG + s) * NHID + f] = sm;
}

__global__ __launch_bounds__(128) void k_readout_comb(const float* __restrict__ pmax,
                                                      const float* __restrict__ psum,
                                                      float* __restrict__ accum, int k) {
    int b = blockIdx.x, f = threadIdx.x;
    float mx = -__builtin_inff(), sm = 0.f;
#pragma unroll
    for (int s = 0; s < RSEG; ++s) {
        mx = fmaxf(mx, pmax[(size_t)(b * RSEG + s) * NHID + f]);
        sm += psum[(size_t)(b * RSEG + s) * NHID + f];
    }
    accum[b * 256 + f]       += mx;
    accum[b * 256 + 128 + f] += sm / (float)k;
}

// ---------------- edge remap (in place) + next-layer degree count ----------------
__global__ void k_remap(int* __restrict__ esrc, int* __restrict__ edst,
                        float* __restrict__ ew, const int* __restrict__ mapping,
                        int* __restrict__ cntN) {
    int e = blockIdx.x * 256 + threadIdx.x;
    if (e >= NE) return;
    int sN = esrc[e], d = edst[e];
    float we = ew[e];
    int ns = mapping[sN], nd = mapping[d];
    bool valid = (ns >= 0) && (nd >= 0) && (we > 0.f);
    esrc[e] = valid ? ns : 0;
    edst[e] = valid ? nd : 0;
    ew[e] = valid ? we : 0.f;
    if (valid) atomicAdd(&cntN[nd], 1);
}

// ---------------- fused layer-3 readout-combine + final linear ----------------
__global__ __launch_bounds__(128) void k_comb_final(const float* __restrict__ pmax,
                                                    const float* __restrict__ psum,
                                                    const float* __restrict__ accum,
                                                    const float* __restrict__ Wl,
                                                    const float* __restrict__ bl,
                                                    float* __restrict__ out, int k) {
    __shared__ float a[256];
    int b = blockIdx.x, f = threadIdx.x;
    float mx = -__builtin_inff(), sm = 0.f;
#pragma unroll
    for (int s = 0; s < RSEG; ++s) {
        mx = fmaxf(mx, pmax[(size_t)(b * RSEG + s) * NHID + f]);
        sm += psum[(size_t)(b * RSEG + s) * NHID + f];
    }
    a[f]       = accum[b * 256 + f] + mx;
    a[128 + f] = accum[b * 256 + 128 + f] + sm / (float)k;
    __syncthreads();
    float s = bl[f];
    for (int i = 0; i < 256; ++i) s = fmaf(a[i], Wl[i * NHID + f], s);
    out[b * NHID + f] = fmaxf(s, 0.f);
}

extern "C" void kernel_launch(void* const* d_in, const int* in_sizes, int n_in,
                              void* d_out, int out_size, void* d_ws, size_t ws_size,
                              hipStream_t stream) {
    const float* x0 = (const float*)d_in[0];
    const float* Wm[3] = {(const float*)d_in[1], (const float*)d_in[5], (const float*)d_in[9]};
    const float* bm[3] = {(const float*)d_in[2], (const float*)d_in[6], (const float*)d_in[10]};
    const float* Wsc[3] = {(const float*)d_in[3], (const float*)d_in[7], (const float*)d_in[11]};
    const float* bsc[3] = {(const float*)d_in[4], (const float*)d_in[8], (const float*)d_in[12]};
    const float* Wl = (const float*)d_in[13];
    const float* bl = (const float*)d_in[14];
    const int*   ei = (const int*)d_in[15];
    float* out = (float*)d_out;

    _Float16* bufA = (_Float16*)d_ws;                       // N0*128 halves (H)
    _Float16* bufB = bufA + (size_t)N0 * NHID;              // N0*128 (X)
    _Float16* WT1  = bufB + (size_t)N0 * NHID;              // 128*256
    _Float16* WT2  = WT1 + 128 * 256;                       // 128*128
    _Float16* WT3  = WT2 + 128 * 128;                       // 128*128
    float* hs     = (float*)(WT3 + 128 * 128);              // N0
    float* score  = hs + N0;                                // N0
    float* gate   = score + N0;                             // N0
    float* accum  = gate + N0;                              // B*256
    float* pmax   = accum + B_GRAPHS * 256;                 // B*RSEG*128
    float* psum   = pmax + B_GRAPHS * RSEG * NHID;          // B*RSEG*128
    int*   cntA   = (int*)(psum + B_GRAPHS * RSEG * NHID);  // N0
    int*   cntB   = cntA + N0;                              // N0
    int*   offs   = cntB + N0;                              // N0
    int*   cursor = offs + N0;                              // N0
    int*   mapping= cursor + N0;                            // N0
    int*   perm   = mapping + N0;                           // N0
    int*   esrc   = perm + N0;                              // NE
    int*   edst   = esrc + NE;                              // NE
    float* ew     = (float*)(edst + NE);                    // NE
    int*   csr_src= (int*)(ew + NE);                        // NE
    float* csr_norm = (float*)(csr_src + NE);               // NE

    _Float16* WTs[3] = {WT1, WT2, WT3};
    const int EG = cdiv(NE, 256);

    k_fill_start<<<cdiv(N0, 256), 256, 0, stream>>>(cntA, accum);
    k_init_edges<<<EG, 256, 0, stream>>>(ei, esrc, edst, ew, cntA);
    k_cvt_all<<<256, 256, 0, stream>>>(Wm[0], Wm[1], Wm[2], WT1, WT2, WT3);

    int npg = NPG0;
    _Float16* Hbuf = bufA; _Float16* Xbuf = bufB;

    for (int layer = 0; layer < 3; ++layer) {
        int N = B_GRAPHS * npg;
        int k = (npg * 4) / 5;   // ceil(0.8*n) exact for 2000/1600/1280
        int NG = cdiv(N, 256);
        int bpg = npg >> 2;      // blocks per graph in k_agg
        int* cnt  = (layer == 1) ? cntB : cntA;
        int* cntN = (layer == 1) ? cntA : cntB;

        if (layer == 0)
            k_gemm_ws<1, 256, 0><<<cdiv(N, 128), 256, 0, stream>>>(x0, WTs[0], perm, gate, Hbuf, N);
        else
            k_gemm_ws<0, 128, 1><<<cdiv(N, 128), 256, 0, stream>>>(Xbuf, WTs[layer], perm, gate, Hbuf, N);
        k_scan<<<B_GRAPHS, 256, 0, stream>>>(cnt, offs, cursor, npg);
        k_fill_csr<<<EG, 256, 0, stream>>>(esrc, edst, ew, cnt, cursor, csr_src, csr_norm);
        k_agg<<<8 * GSLOTS * bpg, 256, 0, stream>>>(Hbuf, csr_src, csr_norm, offs, cnt,
                                                    bm[layer], Wsc[layer], Xbuf, hs, bpg, npg);
        k_score<<<NG, 256, 0, stream>>>(hs, csr_src, csr_norm, offs, cnt, bsc[layer], score, N);
        k_topk<<<B_GRAPHS, 1024, 0, stream>>>(score, mapping, perm, gate, cntN, npg, k);
        k_pool_readout<<<dim3(RSEG, B_GRAPHS), 128, 0, stream>>>(Xbuf, gate, perm, pmax, psum, k);
        if (layer < 2) {
            k_remap<<<EG, 256, 0, stream>>>(esrc, edst, ew, mapping, cntN);
            k_readout_comb<<<B_GRAPHS, 128, 0, stream>>>(pmax, psum, accum, k);
        } else {
            k_comb_final<<<B_GRAPHS, 128, 0, stream>>>(pmax, psum, accum, Wl, bl, out, k);
        }

        npg = k;
    }
}